// Round 15
// baseline (335.440 us; speedup 1.0000x reference)
//
#include <hip/hip_runtime.h>
#include <hip/hip_bf16.h>

// FlexibleGCN forward on MI355X — Round 23 (base R19 = 286.9us best):
//  * Feature-quarter hp/h1: hpq[4][(N+1)][16 bf16] (3.2MB/quarter). agg
//    blocks pinned to quarters via (blockIdx&7)>>1 (XCD pairs) -> each
//    XCD's 4MB L2 holds ONE quarter -> random gather becomes L2-resident
//    (was 31% hit on 12.8MB -> FETCH 154MB/agg).
//  * agg: 4 lanes x uint2 per node, 16 nodes/wave, depth-16 (R14 sched).
//  * mgemm1/mgemm2 bf16 I/O quarter-addressed; fp32 paths unchanged.
//  * staging de-aliased from hp (quarter0 row N would collide).
//  * CSR chain + MFMA dense otherwise R19-identical. 9 dispatches.

constexpr int IN_DIM  = 128;
constexpr int HDIM    = 64;
constexpr int NBLK_A  = 256;   // count/scatter blocks (histg width)
constexpr int BSH     = 8;     // bucket shift: 256 nodes per bucket
constexpr int MAXNB   = 512;   // max buckets supported (N <= 131072)
constexpr int PADSLK  = 1792;  // per-bucket esrc slack: 256 nodes x 7 max pad

typedef short bf16x8 __attribute__((ext_vector_type(8)));
typedef float f32x4  __attribute__((ext_vector_type(4)));

__device__ __forceinline__ float bf2f(unsigned int u) {
    return __uint_as_float(u << 16);
}
__device__ __forceinline__ unsigned short f2bf_bits(float f) {
    __hip_bfloat16 b = __float2bfloat16(f);
    return *(unsigned short*)&b;
}

// ---------- CSR build (R14) ----------

__global__ void binA_count(const int* __restrict__ dst, int* __restrict__ histg,
                           int E, int NB, int chunk) {
    __shared__ int h[MAXNB];
    for (int i = threadIdx.x; i < NB; i += 256) h[i] = 0;
    __syncthreads();
    int beg = blockIdx.x * chunk;
    int end = min(E, beg + chunk);
    for (int e = beg + threadIdx.x; e < end; e += 256)
        atomicAdd(&h[dst[e] >> BSH], 1);
    __syncthreads();
    for (int i = threadIdx.x; i < NB; i += 256)
        histg[i * NBLK_A + blockIdx.x] = h[i];
}

__global__ void binA_scanblocks(int* __restrict__ histg, int* __restrict__ btot) {
    __shared__ int sm[NBLK_A];
    int tid = threadIdx.x;
    int v = histg[blockIdx.x * NBLK_A + tid];
    sm[tid] = v;
    __syncthreads();
    for (int off = 1; off < NBLK_A; off <<= 1) {
        int t = (tid >= off) ? sm[tid - off] : 0;
        __syncthreads();
        sm[tid] += t;
        __syncthreads();
    }
    histg[blockIdx.x * NBLK_A + tid] = sm[tid] - v;   // exclusive
    if (tid == NBLK_A - 1) btot[blockIdx.x] = sm[tid];
}

__device__ __forceinline__ void bucket_scan(const int* __restrict__ btot,
                                            int* bb, int NB) {
    int tid = threadIdx.x;
    for (int i = tid; i < MAXNB; i += 256) bb[i] = (i < NB) ? btot[i] : 0;
    __syncthreads();
    for (int off = 1; off < MAXNB; off <<= 1) {
        int i0 = tid, i1 = tid + 256;
        int t0 = (i0 >= off) ? bb[i0 - off] : 0;
        int t1 = (i1 >= off) ? bb[i1 - off] : 0;
        __syncthreads();
        bb[i0] += t0;
        bb[i1] += t1;
        __syncthreads();
    }
}

__global__ void binA_scatter(const int* __restrict__ src, const int* __restrict__ dst,
                             const int* __restrict__ histg, const int* __restrict__ btot,
                             int* __restrict__ staging, int E, int NB, int chunk) {
    __shared__ int bb[MAXNB];
    __shared__ int cur[MAXNB];
    bucket_scan(btot, bb, NB);
    for (int i = threadIdx.x; i < NB; i += 256)
        cur[i] = (bb[i] - btot[i]) + histg[i * NBLK_A + blockIdx.x];
    __syncthreads();
    int beg = blockIdx.x * chunk;
    int end = min(E, beg + chunk);
    for (int e = beg + threadIdx.x; e < end; e += 256) {
        int s = src[e];
        int d = dst[e];
        int pos = atomicAdd(&cur[d >> BSH], 1);
        staging[pos] = (s << BSH) | (d & 255);    // src<2^17, local dst 8 bits
    }
}

__global__ void binB_finalize(const int* __restrict__ staging, const int* __restrict__ btot,
                              int2* __restrict__ rows, int* __restrict__ esrc,
                              float* __restrict__ dinv, uint2* __restrict__ hpq,
                              int N, int NB, int NP1) {
    __shared__ int bb[MAXNB];
    __shared__ int cnt[256], sm[256], cur[256];
    int tid = threadIdx.x;
    int b = blockIdx.x;
    bucket_scan(btot, bb, NB);
    int node0 = b << BSH;
    int nloc = min(256, N - node0);
    int eend = bb[b];
    int ebeg = eend - btot[b];
    int ebegP = ebeg + b * PADSLK;            // padded bucket base
    cnt[tid] = 0;
    __syncthreads();
    for (int e = ebeg + tid; e < eend; e += 256)
        atomicAdd(&cnt[staging[e] & 255], 1);
    __syncthreads();
    int v = cnt[tid];
    int pv = (v + 7) & ~7;                    // padded count
    sm[tid] = pv;
    __syncthreads();
    for (int off = 1; off < 256; off <<= 1) {
        int t = (tid >= off) ? sm[tid - off] : 0;
        __syncthreads();
        sm[tid] += t;
        __syncthreads();
    }
    int excl = sm[tid] - pv;                  // padded exclusive offset
    cur[tid] = excl;
    __syncthreads();
    if (tid < nloc) {
        rows[node0 + tid] = make_int2(ebegP + excl, ebegP + excl + pv);
        dinv[node0 + tid] = rsqrtf((float)v + 1.0f);   // +1 self-loop
        for (int q = v; q < pv; ++q)          // fill pad slots -> zero row
            esrc[ebegP + excl + q] = N;
    }
    // zero gather row N in all 4 feature quarters (8B x 16 = 128B)
    if (b == 0 && tid < 16)
        hpq[((size_t)(tid >> 2) * NP1 + N) * 4 + (tid & 3)] = make_uint2(0u, 0u);
    for (int e = ebeg + tid; e < eend; e += 256) {
        int p = staging[e];
        int pos = ebegP + atomicAdd(&cur[p & 255], 1);
        esrc[pos] = p >> BSH;
    }
}

// ---------- dense layers: MFMA (R19 64-row tiles, quarter bf16 I/O) ----------
// Block: 256 thr = 4 waves; tile 64 rows x 64 cols; wave w owns rows
// w*16..w*16+15. K steps of 32 (mfma_f32_16x16x32_bf16).
// bf16 inputs/outputs are quarter-split: buf[q][(N+1)][16 bf16], q=col/16.
template<int K, bool IBF16, bool SCALE, bool BIAS, bool OBF16>
__device__ __forceinline__ void mfma_gemm_body(
        const void* __restrict__ Xv, const float* __restrict__ W,
        const float* __restrict__ bias, const float* __restrict__ dinv,
        void* __restrict__ Yv, int n, int NP1) {
    constexpr int STR = K + 8;                      // bf16 elems per row
    __shared__ short SMEM[2 * 64 * STR];            // At | Wt
    __shared__ float dls[64];
    short* At = SMEM;
    short* Wt = SMEM + 64 * STR;
    const int tid = threadIdx.x;
    const int node0 = blockIdx.x * 64;
    const int w = tid >> 6;
    const int lane = tid & 63;
    const int lrow = lane & 15;                     // A row / B col / D col
    const int khal = lane >> 4;                     // k-group 0..3

    // ---- stage A (bf16) ----
    if (IBF16) {                                    // quarter-split bf16 (K=64)
#pragma unroll
        for (int i = 0; i < K / 32; ++i) {
            int s = tid + i * 256;                  // 512 uint4 chunks
            int row = s >> 3, j = s & 7;
            int grow = node0 + row;
            uint4 u = make_uint4(0, 0, 0, 0);
            if (grow < n)
                u = ((const uint4*)Xv)[((size_t)(j >> 1) * NP1 + grow) * 2 + (j & 1)];
            *(uint4*)&At[row * STR + j * 8] = u;
        }
    } else {                                        // fp32 full rows -> cvt
#pragma unroll
        for (int i = 0; i < K / 16; ++i) {
            int s = tid + i * 256;                  // 64*(K/4) float4 chunks
            int row = s / (K / 4), kq = s % (K / 4);
            int grow = node0 + row;
            float4 v = make_float4(0.f, 0.f, 0.f, 0.f);
            if (grow < n)
                v = *(const float4*)&((const float*)Xv)[(size_t)grow * K + kq * 4];
            unsigned short pk[4] = {f2bf_bits(v.x), f2bf_bits(v.y),
                                    f2bf_bits(v.z), f2bf_bits(v.w)};
            *(uint2*)&At[row * STR + kq * 4] = *(uint2*)pk;
        }
    }
    // ---- stage Wt (transposed, bf16) ----
#pragma unroll
    for (int i = 0; i < K / 4; ++i) {
        int s = tid + i * 256;                      // K*64 scalars
        int k = s >> 6, c = s & 63;
        Wt[c * STR + k] = (short)f2bf_bits(W[s]);
    }
    if (SCALE && tid < 64)
        dls[tid] = (node0 + tid < n) ? dinv[node0 + tid] : 1.0f;
    __syncthreads();

    // ---- MFMA ----
    f32x4 acc[4];
#pragma unroll
    for (int ct = 0; ct < 4; ++ct)
#pragma unroll
        for (int r = 0; r < 4; ++r) acc[ct][r] = 0.f;
#pragma unroll
    for (int kt = 0; kt < K / 32; ++kt) {
        int k0 = kt * 32 + khal * 8;
        bf16x8 a = *(bf16x8*)&At[(w * 16 + lrow) * STR + k0];
#pragma unroll
        for (int ct = 0; ct < 4; ++ct) {
            bf16x8 b = *(bf16x8*)&Wt[(ct * 16 + lrow) * STR + k0];
            acc[ct] = __builtin_amdgcn_mfma_f32_16x16x32_bf16(a, b, acc[ct], 0, 0, 0);
        }
    }
    __syncthreads();                                // At/Wt reads done

    // ---- epilogue -> LDS stage (aliases SMEM) ----
    short* Ot = SMEM;                               // [64][72] bf16
    float* Of = (float*)SMEM;                       // [64][68] f32
#pragma unroll
    for (int ct = 0; ct < 4; ++ct) {
#pragma unroll
        for (int r = 0; r < 4; ++r) {
            int row = w * 16 + khal * 4 + r;
            int col = ct * 16 + lrow;
            float v = acc[ct][r];
            if (BIAS) v += bias[col];
            if (SCALE) v *= dls[row];
            if (OBF16) Ot[row * 72 + col] = (short)f2bf_bits(v);
            else       Of[row * 68 + col] = v;
        }
    }
    __syncthreads();

    // ---- coalesced global write ----
    if (OBF16) {                                    // quarter-split bf16
#pragma unroll
        for (int i = 0; i < 2; ++i) {
            int s = tid + i * 256;                  // 512 uint4
            int row = s >> 3, j = s & 7;
            if (node0 + row < n)
                ((uint4*)Yv)[((size_t)(j >> 1) * NP1 + node0 + row) * 2 + (j & 1)] =
                    *(uint4*)&Ot[row * 72 + j * 8];
        }
    } else {
#pragma unroll
        for (int i = 0; i < 4; ++i) {
            int s = tid + i * 256;                  // 1024 float4
            int row = s >> 4, q = s & 15;
            if (node0 + row < n)
                *(float4*)&((float*)Yv)[(size_t)(node0 + row) * 64 + q * 4] =
                    *(float4*)&Of[row * 68 + q * 4];
        }
    }
}

__global__ __launch_bounds__(256, 4) void mgemm1_kernel(
        const float* X, const float* W, const float* dinv, void* Y, int n, int NP1) {
    mfma_gemm_body<IN_DIM, false, true, false, true>(X, W, nullptr, dinv, Y, n, NP1);
}
__global__ __launch_bounds__(256, 4) void mgemm2_kernel(
        const void* X, const float* W, const float* dinv, void* Y, int n, int NP1) {
    mfma_gemm_body<HDIM, true, true, false, true>(X, W, nullptr, dinv, Y, n, NP1);
}
__global__ __launch_bounds__(256, 4) void mfc_kernel(
        const float* X, const float* W, const float* bias, void* Y, int n) {
    mfma_gemm_body<HDIM, false, false, true, false>(X, W, bias, nullptr, Y, n, 0);
}

// ---------- aggregation: quarter-split, XCD-pinned ----------
// Quarter q = (blockIdx&7)>>1: XCD pair {2q,2q+1} only touches hpq[q]
// (3.2MB < 4MB L2). Wave = 16 nodes x 4 lanes; lane j=lane&3 holds feats
// {16q+4j..+3} (uint2 = 8B). Depth-16 batches + depth-8 tail (pad %8).
template<bool OBF16>
__global__ __launch_bounds__(256) void agg_kernel(
        const uint2* __restrict__ hpq, const int* __restrict__ esrc,
        const int2* __restrict__ rows, const float* __restrict__ dinv,
        const float* __restrict__ bias, void* __restrict__ out, int n, int NP1) {
    const int lane = threadIdx.x & 63;
    const int j = lane & 3;
    const int q = ((int)blockIdx.x & 7) >> 1;
    const uint2* hq = hpq + (size_t)q * NP1 * 4;
    const int pb = ((int)blockIdx.x >> 3) * 2 + ((int)blockIdx.x & 1);
    const int step = (gridDim.x >> 2) * 64;
    const float b0 = bias[q * 16 + 4 * j + 0];
    const float b1 = bias[q * 16 + 4 * j + 1];
    const float b2 = bias[q * 16 + 4 * j + 2];
    const float b3 = bias[q * 16 + 4 * j + 3];

    for (int idx = pb * 64 + (threadIdx.x >> 6) * 16 + (lane >> 2);
         idx < n; idx += step) {
        const int2 be = rows[idx];
        uint2 su = hq[(size_t)idx * 4 + j];       // self-loop
        float a0 = bf2f(su.x & 0xffff), a1 = bf2f(su.x >> 16);
        float a2 = bf2f(su.y & 0xffff), a3 = bf2f(su.y >> 16);
        int k = be.x;
        for (; k + 16 <= be.y; k += 16) {         // depth-16 batches
            int s[16];
#pragma unroll
            for (int i = 0; i < 16; ++i)
                s[i] = __builtin_nontemporal_load(&esrc[k + i]);
            uint2 u[16];
#pragma unroll
            for (int i = 0; i < 16; ++i)
                u[i] = hq[(size_t)s[i] * 4 + j];
#pragma unroll
            for (int i = 0; i < 16; ++i) {
                a0 += bf2f(u[i].x & 0xffff); a1 += bf2f(u[i].x >> 16);
                a2 += bf2f(u[i].y & 0xffff); a3 += bf2f(u[i].y >> 16);
            }
        }
        if (k < be.y) {                            // padded => exactly 8 left
            int s[8];
#pragma unroll
            for (int i = 0; i < 8; ++i)
                s[i] = __builtin_nontemporal_load(&esrc[k + i]);
            uint2 u[8];
#pragma unroll
            for (int i = 0; i < 8; ++i)
                u[i] = hq[(size_t)s[i] * 4 + j];
#pragma unroll
            for (int i = 0; i < 8; ++i) {
                a0 += bf2f(u[i].x & 0xffff); a1 += bf2f(u[i].x >> 16);
                a2 += bf2f(u[i].y & 0xffff); a3 += bf2f(u[i].y >> 16);
            }
        }
        const float d = dinv[idx];
        float o0 = fmaxf(fmaf(d, a0, b0), 0.f);
        float o1 = fmaxf(fmaf(d, a1, b1), 0.f);
        float o2 = fmaxf(fmaf(d, a2, b2), 0.f);
        float o3 = fmaxf(fmaf(d, a3, b3), 0.f);

        if (OBF16) {                               // quarter-split bf16 out
            uint2 pk;
            pk.x = (unsigned)f2bf_bits(o0) | ((unsigned)f2bf_bits(o1) << 16);
            pk.y = (unsigned)f2bf_bits(o2) | ((unsigned)f2bf_bits(o3) << 16);
            ((uint2*)out)[((size_t)q * NP1 + idx) * 4 + j] = pk;
        } else {                                   // fp32 emb full rows
            ((float4*)out)[(size_t)idx * 16 + q * 4 + j] = make_float4(o0, o1, o2, o3);
        }
    }
}

extern "C" void kernel_launch(void* const* d_in, const int* in_sizes, int n_in,
                              void* d_out, int out_size, void* d_ws, size_t ws_size,
                              hipStream_t stream) {
    const float* x   = (const float*)d_in[0];
    const float* W1  = (const float*)d_in[1];
    const float* b1  = (const float*)d_in[2];
    const float* W2  = (const float*)d_in[3];
    const float* b2  = (const float*)d_in[4];
    const float* Wfc = (const float*)d_in[5];
    const float* bfc = (const float*)d_in[6];
    const int*  eidx = (const int*)d_in[7];

    const int N = in_sizes[0] / IN_DIM;     // 100000
    const int E = in_sizes[7] / 2;          // 1600000
    const int* src = eidx;
    const int* dst = eidx + E;

    const int NB    = (N + 255) >> BSH;     // 391 buckets
    const int chunk = (E + NBLK_A - 1) / NBLK_A;
    const int EP    = E + NB * PADSLK;      // padded esrc capacity
    const int NP1   = N + 1;                // rows per feature quarter

    // ws layout (ints, 16B-aligned regions). staging separate (quarter0's
    // row N lies inside the old alias window):
    // rows[N] int2 | dinv[N] | histg[NB*256] | btot[512] | staging[E]
    //   | esrc[EP] | hp[4*NP1*16 bf16] | h1[4*NP1*16 bf16]
    int* p = (int*)d_ws;
    int2* rows = (int2*)p;           p += (size_t)2 * N + 2;
    float* dinv = (float*)p;         p += (size_t)((N + 3) & ~3);
    int* histg = p;                  p += (size_t)((NB * NBLK_A + 3) & ~3);
    int* btot = p;                   p += 512;
    int* staging = p;                p += (size_t)((E + 3) & ~3);
    int* esrc = p;                   p += (size_t)((EP + 3) & ~3);
    unsigned short* hp = (unsigned short*)p;   p += (size_t)4 * NP1 * 8;  // 4q*16bf16 = 8 ints/node
    unsigned short* h1 = (unsigned short*)p;   p += (size_t)4 * NP1 * 8;

    float* emb    = (float*)d_out;
    float* logits = emb + (size_t)N * HDIM;

    const int mB = (N + 63) / 64;           // 1563 MFMA tiles
    const int aBlocks = 2048;               // 256 CU x 8, multiple of 8

    // ---- CSR build (R14) ----
    binA_count<<<NBLK_A, 256, 0, stream>>>(dst, histg, E, NB, chunk);
    binA_scanblocks<<<NB, NBLK_A, 0, stream>>>(histg, btot);
    binA_scatter<<<NBLK_A, 256, 0, stream>>>(src, dst, histg, btot, staging, E, NB, chunk);
    binB_finalize<<<NB, 256, 0, stream>>>(staging, btot, rows, esrc, dinv,
                                          (uint2*)hp, N, NB, NP1);

    // ---- layer 1 ----
    mgemm1_kernel<<<mB, 256, 0, stream>>>(x, W1, dinv, hp, N, NP1);
    agg_kernel<true><<<aBlocks, 256, 0, stream>>>(
        (const uint2*)hp, esrc, rows, dinv, b1, h1, N, NP1);

    // ---- layer 2 ----
    mgemm2_kernel<<<mB, 256, 0, stream>>>(h1, W2, dinv, hp, N, NP1);
    agg_kernel<false><<<aBlocks, 256, 0, stream>>>(
        (const uint2*)hp, esrc, rows, dinv, b2, emb, N, NP1);

    // ---- FC head ----
    mfc_kernel<<<mB, 256, 0, stream>>>(emb, Wfc, bfc, logits, N);
}

// Round 16
// 265.687 us; speedup vs baseline: 1.2625x; 1.2625x over previous
//
#include <hip/hip_runtime.h>
#include <hip/hip_bf16.h>

// FlexibleGCN forward on MI355X — Round 24 (base R19 = 286.9us best):
//  * Feature-HALF hp/h1: hph[2][(N+1)][32 bf16] (6.4MB/half, 64B rows).
//    Gather = 4 lanes x uint4 = exactly ONE 64B line per edge (2E line
//    touches, same as R14; R23's 32B quarters were 4E). XCD-quad pinning
//    (h=(bid&7)>>2) -> L2 hit ~62% vs R14's 31%.
//  * agg: 16 nodes/wave x 4 lanes, depth-16 + depth-8 tail (R14 sched).
//  * mgemm1/mgemm2 bf16 I/O half-addressed; fp32 paths unchanged.
//  * CSR chain + MFMA dense R19-identical. 9 dispatches.

constexpr int IN_DIM  = 128;
constexpr int HDIM    = 64;
constexpr int NBLK_A  = 256;   // count/scatter blocks (histg width)
constexpr int BSH     = 8;     // bucket shift: 256 nodes per bucket
constexpr int MAXNB   = 512;   // max buckets supported (N <= 131072)
constexpr int PADSLK  = 1792;  // per-bucket esrc slack: 256 nodes x 7 max pad

typedef short bf16x8 __attribute__((ext_vector_type(8)));
typedef float f32x4  __attribute__((ext_vector_type(4)));

__device__ __forceinline__ float bf2f(unsigned int u) {
    return __uint_as_float(u << 16);
}
__device__ __forceinline__ unsigned short f2bf_bits(float f) {
    __hip_bfloat16 b = __float2bfloat16(f);
    return *(unsigned short*)&b;
}

// ---------- CSR build (R14) ----------

__global__ void binA_count(const int* __restrict__ dst, int* __restrict__ histg,
                           int E, int NB, int chunk) {
    __shared__ int h[MAXNB];
    for (int i = threadIdx.x; i < NB; i += 256) h[i] = 0;
    __syncthreads();
    int beg = blockIdx.x * chunk;
    int end = min(E, beg + chunk);
    for (int e = beg + threadIdx.x; e < end; e += 256)
        atomicAdd(&h[dst[e] >> BSH], 1);
    __syncthreads();
    for (int i = threadIdx.x; i < NB; i += 256)
        histg[i * NBLK_A + blockIdx.x] = h[i];
}

__global__ void binA_scanblocks(int* __restrict__ histg, int* __restrict__ btot) {
    __shared__ int sm[NBLK_A];
    int tid = threadIdx.x;
    int v = histg[blockIdx.x * NBLK_A + tid];
    sm[tid] = v;
    __syncthreads();
    for (int off = 1; off < NBLK_A; off <<= 1) {
        int t = (tid >= off) ? sm[tid - off] : 0;
        __syncthreads();
        sm[tid] += t;
        __syncthreads();
    }
    histg[blockIdx.x * NBLK_A + tid] = sm[tid] - v;   // exclusive
    if (tid == NBLK_A - 1) btot[blockIdx.x] = sm[tid];
}

__device__ __forceinline__ void bucket_scan(const int* __restrict__ btot,
                                            int* bb, int NB) {
    int tid = threadIdx.x;
    for (int i = tid; i < MAXNB; i += 256) bb[i] = (i < NB) ? btot[i] : 0;
    __syncthreads();
    for (int off = 1; off < MAXNB; off <<= 1) {
        int i0 = tid, i1 = tid + 256;
        int t0 = (i0 >= off) ? bb[i0 - off] : 0;
        int t1 = (i1 >= off) ? bb[i1 - off] : 0;
        __syncthreads();
        bb[i0] += t0;
        bb[i1] += t1;
        __syncthreads();
    }
}

__global__ void binA_scatter(const int* __restrict__ src, const int* __restrict__ dst,
                             const int* __restrict__ histg, const int* __restrict__ btot,
                             int* __restrict__ staging, int E, int NB, int chunk) {
    __shared__ int bb[MAXNB];
    __shared__ int cur[MAXNB];
    bucket_scan(btot, bb, NB);
    for (int i = threadIdx.x; i < NB; i += 256)
        cur[i] = (bb[i] - btot[i]) + histg[i * NBLK_A + blockIdx.x];
    __syncthreads();
    int beg = blockIdx.x * chunk;
    int end = min(E, beg + chunk);
    for (int e = beg + threadIdx.x; e < end; e += 256) {
        int s = src[e];
        int d = dst[e];
        int pos = atomicAdd(&cur[d >> BSH], 1);
        staging[pos] = (s << BSH) | (d & 255);    // src<2^17, local dst 8 bits
    }
}

__global__ void binB_finalize(const int* __restrict__ staging, const int* __restrict__ btot,
                              int2* __restrict__ rows, int* __restrict__ esrc,
                              float* __restrict__ dinv, uint4* __restrict__ hph,
                              int N, int NB, int NP1) {
    __shared__ int bb[MAXNB];
    __shared__ int cnt[256], sm[256], cur[256];
    int tid = threadIdx.x;
    int b = blockIdx.x;
    bucket_scan(btot, bb, NB);
    int node0 = b << BSH;
    int nloc = min(256, N - node0);
    int eend = bb[b];
    int ebeg = eend - btot[b];
    int ebegP = ebeg + b * PADSLK;            // padded bucket base
    cnt[tid] = 0;
    __syncthreads();
    for (int e = ebeg + tid; e < eend; e += 256)
        atomicAdd(&cnt[staging[e] & 255], 1);
    __syncthreads();
    int v = cnt[tid];
    int pv = (v + 7) & ~7;                    // padded count
    sm[tid] = pv;
    __syncthreads();
    for (int off = 1; off < 256; off <<= 1) {
        int t = (tid >= off) ? sm[tid - off] : 0;
        __syncthreads();
        sm[tid] += t;
        __syncthreads();
    }
    int excl = sm[tid] - pv;                  // padded exclusive offset
    cur[tid] = excl;
    __syncthreads();
    if (tid < nloc) {
        rows[node0 + tid] = make_int2(ebegP + excl, ebegP + excl + pv);
        dinv[node0 + tid] = rsqrtf((float)v + 1.0f);   // +1 self-loop
        for (int q = v; q < pv; ++q)          // fill pad slots -> zero row
            esrc[ebegP + excl + q] = N;
    }
    // zero gather row N in both feature halves (2 x 64B)
    if (b == 0 && tid < 8)
        hph[((size_t)(tid >> 2) * NP1 + N) * 4 + (tid & 3)] = make_uint4(0, 0, 0, 0);
    for (int e = ebeg + tid; e < eend; e += 256) {
        int p = staging[e];
        int pos = ebegP + atomicAdd(&cur[p & 255], 1);
        esrc[pos] = p >> BSH;
    }
}

// ---------- dense layers: MFMA (R19 64-row tiles, half bf16 I/O) ----------
// Block: 256 thr = 4 waves; tile 64 rows x 64 cols; wave w owns rows
// w*16..w*16+15. K steps of 32 (mfma_f32_16x16x32_bf16).
// bf16 inputs/outputs are half-split: buf[h][(N+1)][32 bf16], h=col/32.
template<int K, bool IBF16, bool SCALE, bool BIAS, bool OBF16>
__device__ __forceinline__ void mfma_gemm_body(
        const void* __restrict__ Xv, const float* __restrict__ W,
        const float* __restrict__ bias, const float* __restrict__ dinv,
        void* __restrict__ Yv, int n, int NP1) {
    constexpr int STR = K + 8;                      // bf16 elems per row
    __shared__ short SMEM[2 * 64 * STR];            // At | Wt
    __shared__ float dls[64];
    short* At = SMEM;
    short* Wt = SMEM + 64 * STR;
    const int tid = threadIdx.x;
    const int node0 = blockIdx.x * 64;
    const int w = tid >> 6;
    const int lane = tid & 63;
    const int lrow = lane & 15;                     // A row / B col / D col
    const int khal = lane >> 4;                     // k-group 0..3

    // ---- stage A (bf16) ----
    if (IBF16) {                                    // half-split bf16 (K=64)
#pragma unroll
        for (int i = 0; i < K / 32; ++i) {
            int s = tid + i * 256;                  // 512 uint4 chunks
            int row = s >> 3, j = s & 7;
            int grow = node0 + row;
            uint4 u = make_uint4(0, 0, 0, 0);
            if (grow < n)
                u = ((const uint4*)Xv)[((size_t)(j >> 2) * NP1 + grow) * 4 + (j & 3)];
            *(uint4*)&At[row * STR + j * 8] = u;
        }
    } else {                                        // fp32 full rows -> cvt
#pragma unroll
        for (int i = 0; i < K / 16; ++i) {
            int s = tid + i * 256;                  // 64*(K/4) float4 chunks
            int row = s / (K / 4), kq = s % (K / 4);
            int grow = node0 + row;
            float4 v = make_float4(0.f, 0.f, 0.f, 0.f);
            if (grow < n)
                v = *(const float4*)&((const float*)Xv)[(size_t)grow * K + kq * 4];
            unsigned short pk[4] = {f2bf_bits(v.x), f2bf_bits(v.y),
                                    f2bf_bits(v.z), f2bf_bits(v.w)};
            *(uint2*)&At[row * STR + kq * 4] = *(uint2*)pk;
        }
    }
    // ---- stage Wt (transposed, bf16) ----
#pragma unroll
    for (int i = 0; i < K / 4; ++i) {
        int s = tid + i * 256;                      // K*64 scalars
        int k = s >> 6, c = s & 63;
        Wt[c * STR + k] = (short)f2bf_bits(W[s]);
    }
    if (SCALE && tid < 64)
        dls[tid] = (node0 + tid < n) ? dinv[node0 + tid] : 1.0f;
    __syncthreads();

    // ---- MFMA ----
    f32x4 acc[4];
#pragma unroll
    for (int ct = 0; ct < 4; ++ct)
#pragma unroll
        for (int r = 0; r < 4; ++r) acc[ct][r] = 0.f;
#pragma unroll
    for (int kt = 0; kt < K / 32; ++kt) {
        int k0 = kt * 32 + khal * 8;
        bf16x8 a = *(bf16x8*)&At[(w * 16 + lrow) * STR + k0];
#pragma unroll
        for (int ct = 0; ct < 4; ++ct) {
            bf16x8 b = *(bf16x8*)&Wt[(ct * 16 + lrow) * STR + k0];
            acc[ct] = __builtin_amdgcn_mfma_f32_16x16x32_bf16(a, b, acc[ct], 0, 0, 0);
        }
    }
    __syncthreads();                                // At/Wt reads done

    // ---- epilogue -> LDS stage (aliases SMEM) ----
    short* Ot = SMEM;                               // [64][72] bf16
    float* Of = (float*)SMEM;                       // [64][68] f32
#pragma unroll
    for (int ct = 0; ct < 4; ++ct) {
#pragma unroll
        for (int r = 0; r < 4; ++r) {
            int row = w * 16 + khal * 4 + r;
            int col = ct * 16 + lrow;
            float v = acc[ct][r];
            if (BIAS) v += bias[col];
            if (SCALE) v *= dls[row];
            if (OBF16) Ot[row * 72 + col] = (short)f2bf_bits(v);
            else       Of[row * 68 + col] = v;
        }
    }
    __syncthreads();

    // ---- coalesced global write ----
    if (OBF16) {                                    // half-split bf16
#pragma unroll
        for (int i = 0; i < 2; ++i) {
            int s = tid + i * 256;                  // 512 uint4
            int row = s >> 3, j = s & 7;
            if (node0 + row < n)
                ((uint4*)Yv)[((size_t)(j >> 2) * NP1 + node0 + row) * 4 + (j & 3)] =
                    *(uint4*)&Ot[row * 72 + j * 8];
        }
    } else {
#pragma unroll
        for (int i = 0; i < 4; ++i) {
            int s = tid + i * 256;                  // 1024 float4
            int row = s >> 4, q = s & 15;
            if (node0 + row < n)
                *(float4*)&((float*)Yv)[(size_t)(node0 + row) * 64 + q * 4] =
                    *(float4*)&Of[row * 68 + q * 4];
        }
    }
}

__global__ __launch_bounds__(256, 4) void mgemm1_kernel(
        const float* X, const float* W, const float* dinv, void* Y, int n, int NP1) {
    mfma_gemm_body<IN_DIM, false, true, false, true>(X, W, nullptr, dinv, Y, n, NP1);
}
__global__ __launch_bounds__(256, 4) void mgemm2_kernel(
        const void* X, const float* W, const float* dinv, void* Y, int n, int NP1) {
    mfma_gemm_body<HDIM, true, true, false, true>(X, W, nullptr, dinv, Y, n, NP1);
}
__global__ __launch_bounds__(256, 4) void mfc_kernel(
        const float* X, const float* W, const float* bias, void* Y, int n) {
    mfma_gemm_body<HDIM, false, false, true, false>(X, W, bias, nullptr, Y, n, 0);
}

// ---------- aggregation: half-split, XCD-quad pinned ----------
// Half h = (blockIdx&7)>>2: XCD quad only touches hph[h] (6.4MB; ~62% L2
// hit). Wave = 16 nodes x 4 lanes; lane j=lane&3 loads uint4 (16B) of the
// 64B half-row -> ONE 64B line per edge (2E total line touches, = R14).
// Depth-16 batches + depth-8 tail (pad %8). 16 edges per wave-inst.
template<bool OBF16>
__global__ __launch_bounds__(256) void agg_kernel(
        const uint4* __restrict__ hph, const int* __restrict__ esrc,
        const int2* __restrict__ rows, const float* __restrict__ dinv,
        const float* __restrict__ bias, void* __restrict__ out, int n, int NP1) {
    const int lane = threadIdx.x & 63;
    const int j = lane & 3;
    const int h = ((int)blockIdx.x & 7) >> 2;
    const uint4* hq = hph + (size_t)h * NP1 * 4;
    const int pb = (((int)blockIdx.x >> 3) << 2) | ((int)blockIdx.x & 3);
    const int step = (gridDim.x >> 1) * 64;
    float bb[8];
#pragma unroll
    for (int t = 0; t < 8; ++t) bb[t] = bias[h * 32 + 8 * j + t];

    for (int idx = pb * 64 + (threadIdx.x >> 6) * 16 + (lane >> 2);
         idx < n; idx += step) {
        const int2 be = rows[idx];
        float a[8];
        {   // self-loop
            uint4 u = hq[(size_t)idx * 4 + j];
            a[0] = bf2f(u.x & 0xffff); a[1] = bf2f(u.x >> 16);
            a[2] = bf2f(u.y & 0xffff); a[3] = bf2f(u.y >> 16);
            a[4] = bf2f(u.z & 0xffff); a[5] = bf2f(u.z >> 16);
            a[6] = bf2f(u.w & 0xffff); a[7] = bf2f(u.w >> 16);
        }
        int k = be.x;
        for (; k + 16 <= be.y; k += 16) {         // depth-16 batches
            int s[16];
#pragma unroll
            for (int i = 0; i < 16; ++i)
                s[i] = __builtin_nontemporal_load(&esrc[k + i]);
            uint4 u[16];
#pragma unroll
            for (int i = 0; i < 16; ++i)
                u[i] = hq[(size_t)s[i] * 4 + j];
#pragma unroll
            for (int i = 0; i < 16; ++i) {
                a[0] += bf2f(u[i].x & 0xffff); a[1] += bf2f(u[i].x >> 16);
                a[2] += bf2f(u[i].y & 0xffff); a[3] += bf2f(u[i].y >> 16);
                a[4] += bf2f(u[i].z & 0xffff); a[5] += bf2f(u[i].z >> 16);
                a[6] += bf2f(u[i].w & 0xffff); a[7] += bf2f(u[i].w >> 16);
            }
        }
        if (k < be.y) {                            // padded => exactly 8 left
            int s[8];
#pragma unroll
            for (int i = 0; i < 8; ++i)
                s[i] = __builtin_nontemporal_load(&esrc[k + i]);
            uint4 u[8];
#pragma unroll
            for (int i = 0; i < 8; ++i)
                u[i] = hq[(size_t)s[i] * 4 + j];
#pragma unroll
            for (int i = 0; i < 8; ++i) {
                a[0] += bf2f(u[i].x & 0xffff); a[1] += bf2f(u[i].x >> 16);
                a[2] += bf2f(u[i].y & 0xffff); a[3] += bf2f(u[i].y >> 16);
                a[4] += bf2f(u[i].z & 0xffff); a[5] += bf2f(u[i].z >> 16);
                a[6] += bf2f(u[i].w & 0xffff); a[7] += bf2f(u[i].w >> 16);
            }
        }
        const float d = dinv[idx];
        float o[8];
#pragma unroll
        for (int t = 0; t < 8; ++t)
            o[t] = fmaxf(fmaf(d, a[t], bb[t]), 0.f);

        if (OBF16) {                               // half-split bf16 out
            uint4 pk;
            pk.x = (unsigned)f2bf_bits(o[0]) | ((unsigned)f2bf_bits(o[1]) << 16);
            pk.y = (unsigned)f2bf_bits(o[2]) | ((unsigned)f2bf_bits(o[3]) << 16);
            pk.z = (unsigned)f2bf_bits(o[4]) | ((unsigned)f2bf_bits(o[5]) << 16);
            pk.w = (unsigned)f2bf_bits(o[6]) | ((unsigned)f2bf_bits(o[7]) << 16);
            ((uint4*)out)[((size_t)h * NP1 + idx) * 4 + j] = pk;
        } else {                                   // fp32 emb full rows
            ((float4*)out)[(size_t)idx * 16 + h * 8 + 2 * j]     = make_float4(o[0], o[1], o[2], o[3]);
            ((float4*)out)[(size_t)idx * 16 + h * 8 + 2 * j + 1] = make_float4(o[4], o[5], o[6], o[7]);
        }
    }
}

extern "C" void kernel_launch(void* const* d_in, const int* in_sizes, int n_in,
                              void* d_out, int out_size, void* d_ws, size_t ws_size,
                              hipStream_t stream) {
    const float* x   = (const float*)d_in[0];
    const float* W1  = (const float*)d_in[1];
    const float* b1  = (const float*)d_in[2];
    const float* W2  = (const float*)d_in[3];
    const float* b2  = (const float*)d_in[4];
    const float* Wfc = (const float*)d_in[5];
    const float* bfc = (const float*)d_in[6];
    const int*  eidx = (const int*)d_in[7];

    const int N = in_sizes[0] / IN_DIM;     // 100000
    const int E = in_sizes[7] / 2;          // 1600000
    const int* src = eidx;
    const int* dst = eidx + E;

    const int NB    = (N + 255) >> BSH;     // 391 buckets
    const int chunk = (E + NBLK_A - 1) / NBLK_A;
    const int EP    = E + NB * PADSLK;      // padded esrc capacity
    const int NP1   = N + 1;                // rows per feature half

    // ws layout (ints, regions 16B-aligned; hp/h1 64B-aligned for
    // one-line half-rows):
    // rows[N] int2 | dinv[N] | histg[NB*256] | btot[512] | staging[E]
    //   | esrc[EP] | hp[2*NP1*32 bf16] | h1[2*NP1*32 bf16]
    int* p = (int*)d_ws;
    int2* rows = (int2*)p;           p += (size_t)2 * N + 2;
    float* dinv = (float*)p;         p += (size_t)((N + 3) & ~3);
    int* histg = p;                  p += (size_t)((NB * NBLK_A + 3) & ~3);
    int* btot = p;                   p += 512;
    int* staging = p;                p += (size_t)((E + 3) & ~3);
    int* esrc = p;                   p += (size_t)((EP + 3) & ~3);
    p = (int*)(((uintptr_t)p + 63) & ~(uintptr_t)63);   // 64B align
    unsigned short* hp = (unsigned short*)p;   p += (size_t)2 * NP1 * 16;  // 2h*32bf16
    unsigned short* h1 = (unsigned short*)p;   p += (size_t)2 * NP1 * 16;

    float* emb    = (float*)d_out;
    float* logits = emb + (size_t)N * HDIM;

    const int mB = (N + 63) / 64;           // 1563 MFMA tiles
    const int aBlocks = 2048;               // 256 CU x 8, multiple of 8

    // ---- CSR build (R14) ----
    binA_count<<<NBLK_A, 256, 0, stream>>>(dst, histg, E, NB, chunk);
    binA_scanblocks<<<NB, NBLK_A, 0, stream>>>(histg, btot);
    binA_scatter<<<NBLK_A, 256, 0, stream>>>(src, dst, histg, btot, staging, E, NB, chunk);
    binB_finalize<<<NB, 256, 0, stream>>>(staging, btot, rows, esrc, dinv,
                                          (uint4*)hp, N, NB, NP1);

    // ---- layer 1 ----
    mgemm1_kernel<<<mB, 256, 0, stream>>>(x, W1, dinv, hp, N, NP1);
    agg_kernel<true><<<aBlocks, 256, 0, stream>>>(
        (const uint4*)hp, esrc, rows, dinv, b1, h1, N, NP1);

    // ---- layer 2 ----
    mgemm2_kernel<<<mB, 256, 0, stream>>>(h1, W2, dinv, hp, N, NP1);
    agg_kernel<false><<<aBlocks, 256, 0, stream>>>(
        (const uint4*)hp, esrc, rows, dinv, b2, emb, N, NP1);

    // ---- FC head ----
    mfc_kernel<<<mB, 256, 0, stream>>>(emb, Wfc, bfc, logits, N);
}